// Round 12
// baseline (99.474 us; speedup 1.0000x reference)
//
#include <hip/hip_runtime.h>

#define D  128   // EMB
#define KN 128   // K_N
#define NB 8     // batch rows per block (grid = 512 -> 2 blocks/CU)
#define LOG2E 1.44269504088896340736f

typedef float f32x4  __attribute__((ext_vector_type(4)));
typedef float f32x16 __attribute__((ext_vector_type(16)));
typedef short s16x8  __attribute__((ext_vector_type(8)));   // 8 bf16 (4 VGPR)

__device__ __forceinline__ float negexp(float v) {              // e^{-v}
    return __builtin_amdgcn_exp2f(v * -LOG2E);
}
__device__ __forceinline__ float sigf(float x) {                // sigmoid
    return __builtin_amdgcn_rcpf(1.0f + negexp(x));
}
__device__ __forceinline__ unsigned short f2bf(float f) {       // fp32->bf16 RNE
    unsigned u = __float_as_uint(f);
    return (unsigned short)((u + 0x7fffu + ((u >> 16) & 1u)) >> 16);
}
__device__ __forceinline__ float bf2f(unsigned short u) {
    return __uint_as_float(((unsigned)u) << 16);
}
__device__ __forceinline__ s16x8 pack8(float4 a, float4 b) {
    s16x8 r;
    r[0]=(short)f2bf(a.x); r[1]=(short)f2bf(a.y); r[2]=(short)f2bf(a.z); r[3]=(short)f2bf(a.w);
    r[4]=(short)f2bf(b.x); r[5]=(short)f2bf(b.y); r[6]=(short)f2bf(b.z); r[7]=(short)f2bf(b.w);
    return r;
}
__device__ __forceinline__ s16x8 pack8abs(float4 a, float4 b) {
    s16x8 r;
    r[0]=(short)f2bf(fabsf(a.x)); r[1]=(short)f2bf(fabsf(a.y)); r[2]=(short)f2bf(fabsf(a.z)); r[3]=(short)f2bf(fabsf(a.w));
    r[4]=(short)f2bf(fabsf(b.x)); r[5]=(short)f2bf(fabsf(b.y)); r[6]=(short)f2bf(fabsf(b.z)); r[7]=(short)f2bf(fabsf(b.w));
    return r;
}

// phase-B core: 2 elements (k=2l,2l+1) of one (b,e)
#define CORE(EA1, EA2, T, PZ, A0, A1) do {                                   \
    float x0_ = fmaf((EA1), (T).x, 1.0f);                                    \
    float x1_ = fmaf((EA1), (T).y, 1.0f);                                    \
    float y0_ = fmaf((EA2), (T).z, 1.0f);                                    \
    float y1_ = fmaf((EA2), (T).w, 1.0f);                                    \
    (A0) = fmaf((y0_ - x0_) * (PZ), __builtin_amdgcn_rcpf(x0_ * y0_), (A0)); \
    (A1) = fmaf((y1_ - x1_) * (PZ), __builtin_amdgcn_rcpf(x1_ * y1_), (A1)); \
} while (0)

// tables write: bf16(exp(-(acc+bias))) into interleaved TAB layout
//   TABh[e*256 + (k>>1)*4 + (k&1) + slot]   (32x32 C-layout per m74)
#define TWRITE2(EBASE, K_, ACC) {                                            \
    const int kof_ = (((K_) >> 1) << 2) + ((K_) & 1) + slot;                 \
    _Pragma("unroll")                                                        \
    for (int r = 0; r < 16; ++r) {                                           \
        int e_ = (EBASE) + (r & 3) + ((r >> 2) << 3) + (g32 << 2);           \
        TABh[e_ * 256 + kof_] = f2bf(negexp(ACC[r] + bias[e_]));             \
    } }

__global__ __launch_bounds__(512, 4) void fused_kernel(
    const int* __restrict__ stu_id, const int* __restrict__ exer_id,
    const float* __restrict__ kq,
    const float* __restrict__ stu_q, const float* __restrict__ exer_k,
    const float* __restrict__ stu_v, const float* __restrict__ exer_v,
    const float* __restrict__ kn,
    const float* __restrict__ W1, const float* __restrict__ b1,
    const float* __restrict__ W2, const float* __restrict__ b2,
    const float* __restrict__ W3, const float* __restrict__ b3,
    float* __restrict__ out, int B)
{
    // LDS map (77824 B -> 2 blocks/CU):
    //   [0,65536)        TAB bf16 ushort4[e][lane] = {E1(2l),E1(2l+1),E2(2l),E2(2l+1)}
    //                      phase A alias: KNs staged in UPPER half [32768,65536)
    //                      pass-0 TWRITE -> [0,32768) (e<64, no clobber);
    //                      pass-1 TWRITE -> [32768,65536) after barrier
    //                      epilogue alias: RED float2[8][8][64] = 32 KB at [0,32768)
    //   [65536,73728)    EAf fp32: b*256 + 2e + {0,1}
    //   [73728,77824)    PZf fp32: r*128 + e
    __shared__ __align__(16) char smemraw[77824];
    __shared__ int sids[NB], eids[NB];

    unsigned short* TABh  = (unsigned short*)smemraw;
    const ushort4*  TABh4 = (const ushort4*)smemraw;
    char*  KNs_base = smemraw + 32768;
    float* EAf = (float*)(smemraw + 65536);
    float* PZf = (float*)(smemraw + 73728);

    const int tid  = threadIdx.x;
    const int b0   = blockIdx.x * NB;
    const int lane = tid & 63, wid = tid >> 6;     // 8 waves
    const int l31 = lane & 31, g32 = lane >> 5;
    const int l15 = lane & 15, g16 = lane >> 4;
    const int bmax = B - 1;

    if (tid < NB) {
        int b = b0 + tid;
        sids[tid] = stu_id[b <= bmax ? b : bmax];
        eids[tid] = exer_id[b <= bmax ? b : bmax];
    }
    // ---- stage kn as bf16 (pack once), row 256B, XOR-swizzled ----
    for (int i = tid; i < 128 * 16; i += 512) {    // 4 iters/thread
        int row = i >> 4, c = i & 15;
        int byt = row * 256 + (((c << 4)) ^ ((row & 7) << 4));
        const float4* sk = (const float4*)(kn + (size_t)row * D + c * 8);
        *(s16x8*)(KNs_base + byt) = pack8(sk[0], sk[1]);
    }
    __syncthreads();

    // ---- tables GEMM, 2 passes x 2 tiles/wave (32 AGPR live, not 64) ----
    // tile j = 2*wid+t: set = j<8 ? W1 : W2; et_local = (wid>>1)&1; kt = 2*(wid&1)+t
    // pass p covers global e in [64p, 64p+64)
    const float* Wt   = (wid < 4) ? W1 : W2;
    const float* bias = (wid < 4) ? b1 : b2;
    const int slot = (wid < 4) ? 0 : 2;
    const int etl  = (wid >> 1) & 1;
    const int kt0  = (wid & 1) * 2;
    const int kr0  = kt0 * 32 + l31, kr1 = kr0 + 32;
    const int k0_  = kt0 * 32 + l31, k1_ = k0_ + 32;
    const int kswz = (l31 & 7) << 4;

    #pragma unroll 1
    for (int p = 0; p < 2; ++p) {
        f32x16 a0 = {0}, a1 = {0};
        const int er = (2 * p + etl) * 32 + l31;
        #pragma unroll 2
        for (int q = 0; q < 8; ++q) {
            int del = q * 16 + g32 * 8;            // fp32 elem offset in W row
            int dby = q * 32 + g32 * 16;           // byte offset in staged kn row
            const float4* pw = (const float4*)(Wt + (size_t)er * (2 * D) + D + del);
            s16x8 a_ = pack8abs(pw[0], pw[1]);
            s16x8 f0 = *(const s16x8*)(KNs_base + kr0 * 256 + (dby ^ kswz));
            s16x8 f1 = *(const s16x8*)(KNs_base + kr1 * 256 + (dby ^ kswz));
            a0 = __builtin_amdgcn_mfma_f32_32x32x16_bf16(a_, f0, a0, 0, 0, 0);
            a1 = __builtin_amdgcn_mfma_f32_32x32x16_bf16(a_, f1, a1, 0, 0, 0);
        }
        if (p == 1) __syncthreads();   // all KNs reads done -> upper half writable
        const int ebase = (2 * p + etl) * 32;
        TWRITE2(ebase, k0_, a0)
        TWRITE2(ebase, k1_, a1)
    }

    // ---- prep GEMM: C[8b x 16e], e-tile = wid; A rows 8-15 dup of 0-7 ----
    {
        const int bi = l15 & 7;
        const int sid_l = sids[bi], eid_l = eids[bi];
        const int erow = wid * 16 + l15;
        f32x4 accS = {0, 0, 0, 0}, accE = {0, 0, 0, 0};
        #pragma unroll 1
        for (int q = 0; q < 4; ++q) {
            int d = q * 32 + g16 * 8;
            const float4* pa = (const float4*)(stu_v + (size_t)sid_l * D + d);
            const float4* pe = (const float4*)(exer_v + (size_t)eid_l * D + d);
            const float4* pb = (const float4*)(W1 + (size_t)erow * (2 * D) + d);
            const float4* pc = (const float4*)(W2 + (size_t)erow * (2 * D) + d);
            accS = __builtin_amdgcn_mfma_f32_16x16x32_bf16(
                pack8(pa[0], pa[1]), pack8abs(pb[0], pb[1]), accS, 0, 0, 0);
            accE = __builtin_amdgcn_mfma_f32_16x16x32_bf16(
                pack8(pe[0], pe[1]), pack8abs(pc[0], pc[1]), accE, 0, 0, 0);
        }
        #pragma unroll
        for (int r = 0; r < 4; ++r) {              // C row = g16*4+r, col e = erow
            int brow = g16 * 4 + r;
            if (brow < NB) {
                int eo = brow * 256 + 2 * erow;
                EAf[eo]     = negexp(accS[r]);
                EAf[eo + 1] = negexp(accE[r]);
            }
        }
    }
    // ---- PZ: wave w handles row w ----
    {
        const int r = wid;
        int b = b0 + r; b = b <= bmax ? b : bmax;
        const int sid = stu_id[b], eid = exer_id[b];   // wave-uniform
        float2 sq = *(const float2*)(stu_q + (size_t)sid * D + 2 * lane);
        float2 ek = *(const float2*)(exer_k + (size_t)eid * D + 2 * lane);
        float2 w3 = *(const float2*)(W3 + 2 * lane);
        float2 z;
        z.x = sigf(sq.x * ek.x) * fabsf(w3.x);
        z.y = sigf(sq.y * ek.y) * fabsf(w3.y);
        *(float2*)(PZf + r * D + 2 * lane) = z;
    }
    __syncthreads();   // TAB/EA/PZ ready

    // ---------------- Phase B: wave owns e in [16w,16w+16), lane owns k-pair ----
    const float4* EA4 = (const float4*)EAf;
    const float2* PZ2 = (const float2*)PZf;

    float2 acc[NB];
    #pragma unroll
    for (int r = 0; r < NB; ++r) acc[r] = make_float2(0.f, 0.f);

    #pragma unroll
    for (int jj = 0; jj < 8; ++jj) {
        const int e0 = wid * 16 + 2 * jj;
        const int j  = wid * 8 + jj;
        ushort4 h0 = TABh4[e0 * 64 + lane];        // b64 LDS read, 2-way (free)
        ushort4 h1 = TABh4[(e0 + 1) * 64 + lane];
        float4 t0 = make_float4(bf2f(h0.x), bf2f(h0.y), bf2f(h0.z), bf2f(h0.w));
        float4 t1 = make_float4(bf2f(h1.x), bf2f(h1.y), bf2f(h1.z), bf2f(h1.w));
        #pragma unroll
        for (int r = 0; r < NB; ++r) {
            float4 eA = EA4[r * 64 + j];           // wave-uniform LDS broadcast
            float2 zA = PZ2[r * 64 + j];
            CORE(eA.x, eA.y, t0, zA.x, acc[r].x, acc[r].y);
            CORE(eA.z, eA.w, t1, zA.y, acc[r].x, acc[r].y);
        }
    }
    __syncthreads();                     // all TAB reads done -> RED may alias

    float2* RED = (float2*)smemraw;      // [wave][row][lane] = 32 KB
    #pragma unroll
    for (int r = 0; r < NB; ++r)
        RED[(wid * NB + r) * 64 + lane] = acc[r];
    __syncthreads();

    // ---- cross-wave reduce + epilogue: wave w handles row w ----
    {
        const int r = wid, b = b0 + r;
        float2 s = make_float2(0.f, 0.f);
        #pragma unroll
        for (int w = 0; w < 8; ++w) {
            float2 p = RED[(w * NB + r) * 64 + lane];
            s.x += p.x; s.y += p.y;
        }
        const float b3v = b3[0];
        float o0 = sigf(s.x + b3v), o1 = sigf(s.y + b3v);
        float num = 0.f, den = 0.f;
        if (b < B) {
            float2 kqv = *(const float2*)(kq + (size_t)b * D + 2 * lane);
            num = fmaf(o0, kqv.x, o1 * kqv.y); den = kqv.x + kqv.y;
        }
        #pragma unroll
        for (int off = 32; off > 0; off >>= 1) {
            num += __shfl_xor(num, off); den += __shfl_xor(den, off);
        }
        if (lane == 0 && b < B) out[b] = num / den;
    }
}

// ---------------------------------------------------------------------------
extern "C" void kernel_launch(void* const* d_in, const int* in_sizes, int n_in,
                              void* d_out, int out_size, void* d_ws, size_t ws_size,
                              hipStream_t stream)
{
    const int*   stu_id      = (const int*)  d_in[0];
    const int*   exer_id     = (const int*)  d_in[1];
    const float* kq          = (const float*)d_in[2];
    const float* student_q   = (const float*)d_in[3];
    const float* exercise_k  = (const float*)d_in[4];
    const float* student_v   = (const float*)d_in[5];
    const float* exercise_v  = (const float*)d_in[6];
    const float* knowledge_v = (const float*)d_in[7];
    const float* W1 = (const float*)d_in[8];
    const float* b1 = (const float*)d_in[9];
    const float* W2 = (const float*)d_in[10];
    const float* b2 = (const float*)d_in[11];
    const float* W3 = (const float*)d_in[12];
    const float* b3 = (const float*)d_in[13];
    float* out = (float*)d_out;
    const int B = in_sizes[0];

    int nblk = (B + NB - 1) / NB;
    fused_kernel<<<nblk, 512, 0, stream>>>(
        stu_id, exer_id, kq, student_q, exercise_k, student_v, exercise_v,
        knowledge_v, W1, b1, W2, b2, W3, b3, out, B);
}